// Round 14
// baseline (261.369 us; speedup 1.0000x reference)
//
#include <hip/hip_runtime.h>

// VQ layer, certified one-main-kernel scheme; B streamed L2 -> VGPRs.
// score(t,k) = z_t.e_k - 0.5||e_k||^2 ; argmax_k == argmin_k ||z_t-e_k||^2.
//
// This is the R11 kernel (PASSED, absmax 0.0) with one mechanical change:
// 2 tiles/wave instead of 4, 1024 blocks of 64 tokens instead of 512x128,
// __launch_bounds__(256,4) -> 4 blocks/CU = 4 waves/SIMD with NO spills
// (~115 VGPRs < 128 cap). R12/R13's 8-wave variant failed correctness;
// its only uncleared difference was a 128-VGPR cap on a ~160-VGPR kernel
// (heavy spill). This variant reaches the same 4 waves/SIMD without
// touching the proven merge/repair logic and without register spills.
//
// Pass 1: MFMA bf16x2 3-term, -0.5||e||^2 folded into acc init.
//   DELTA=5e-3 certified by R7/R8/R10/R11 (2e-3 FAILED in R12 - do not lower).
// Repair tail (block-local): bf16x3 6-term exact-class (R5-proven).
//
// d_ws: [0,1.5MB)      emb B-fragments, bf16 3-level, frag-linear
//       [OFF_N,+16KB)  NEGATIVE half-norms: -0.5||e||^2 fp32 per code
// Fallback to pure-fp32 kernel if ws_size too small.

typedef __attribute__((ext_vector_type(8))) short short8;
typedef __attribute__((ext_vector_type(4))) float f32x4;
typedef unsigned int u32;

#define NCHUNK 256                         // 4096 codes / 16 per chunk
#define FRAGS 6                            // 3 levels x 2 K-halves
#define CHUNK_WSB (FRAGS * 64 * 16)        // 6144 B per chunk in ws
#define WSB_BYTES (NCHUNK * CHUNK_WSB)     // 1,572,864
#define OFF_N    WSB_BYTES
#define WS_NEEDED ((size_t)OFF_N + 16384u) // ~1.52 MB
#define DELTA 0.005f                       // certified R7/R8/R10/R11

static __device__ __forceinline__ unsigned short f2bf(float f) {
    u32 u = __builtin_bit_cast(u32, f);
    u += 0x7fffu + ((u >> 16) & 1u);       // RNE; inputs finite Gaussians
    return (unsigned short)(u >> 16);
}
static __device__ __forceinline__ float bf2f(unsigned short h) {
    u32 u = ((u32)h) << 16;
    return __builtin_bit_cast(float, u);
}

// ---- prep: pack emb into 3-level bf16 B-fragments + neg-norms ------------
// 16B-group id = (ck*6 + f)*64 + lane;  f = level*2 + s (s = K-half).
// B-frag (16x16x32): n = lane&15, k = s*32 + (lane>>4)*8 + j.
__global__ void vq_pack_kernel(const float* __restrict__ emb,
                               unsigned short* __restrict__ wsB,
                               float* __restrict__ wsN) {
    int ck    = blockIdx.x;                // 256 blocks x 384 threads
    int f     = threadIdx.x >> 6;
    int lane  = threadIdx.x & 63;
    int level = f >> 1, s = f & 1;
    int code  = ck * 16 + (lane & 15);
    int kb    = s * 32 + (lane >> 4) * 8;
    const float* src = emb + code * 64 + kb;
    short8 o;
#pragma unroll
    for (int j = 0; j < 8; ++j) {
        float x = src[j];
        unsigned short h1 = f2bf(x);
        float r1 = x - bf2f(h1);
        unsigned short h2 = f2bf(r1);
        float r2 = r1 - bf2f(h2);
        unsigned short h3 = f2bf(r2);
        o[j] = (short)(level == 0 ? h1 : (level == 1 ? h2 : h3));
    }
    ((short8*)wsB)[(ck * FRAGS + f) * 64 + lane] = o;

    if (threadIdx.x < 16) {                // exact fp32 NEGATIVE half-norms
        int c = ck * 16 + threadIdx.x;
        const float* e = emb + c * 64;
        float ssum = 0.f;
#pragma unroll
        for (int k = 0; k < 64; ++k) { float v = e[k]; ssum = fmaf(v, v, ssum); }
        wsN[c] = -0.5f * ssum;
    }
}

// ---- main: pass 1 + block-local certified repair -------------------------
// 1024 blocks x 256 threads (4 waves). Block owns 64 tokens.
// Pass 1: wave w: tokens [(w>>1)*32, +32) (2 tiles), chunks [(w&1)*128, +128).
__global__ __launch_bounds__(256, 4) void vq_main_kernel(
    const float* __restrict__ z, const float* __restrict__ emb,
    const unsigned short* __restrict__ wsB, const float* __restrict__ wsN,
    float* __restrict__ out)
{
    __shared__ float sS1[2][64], sS2[2][64];
    __shared__ int   sI1[2][64];
    __shared__ int   sOut[64];
    __shared__ int   sUList[64];
    __shared__ int   sUCnt;
    __shared__ float sRS[4][16];
    __shared__ int   sRI[4][16];

    const int wave = threadIdx.x >> 6;     // 0..3
    const int lane = threadIdx.x & 63;
    const int quad = lane >> 4;
    const int col  = lane & 15;
    const int tg   = wave >> 1;            // 0..1 token subgroup
    const int half = wave & 1;             // codebook half
    const int cbase = half * 128;          // first chunk of this wave's half

    if (threadIdx.x == 0) sUCnt = 0;

    // A fragments, bf16 2-level: a[tile][level][khalf], k = kh*32+quad*8+j
    const int t0 = blockIdx.x * 64 + tg * 32;
    short8 a[2][2][2];
#pragma unroll
    for (int t = 0; t < 2; ++t) {
        const int tok = t0 + t * 16 + col;
        const int b   = tok >> 12;
        const int hw  = tok & 4095;
        const float* zp = z + b * 262144 + hw;
#pragma unroll
        for (int s = 0; s < 2; ++s)
#pragma unroll
            for (int j = 0; j < 8; ++j) {
                int k = s * 32 + quad * 8 + j;
                float x = zp[k * 4096];    // coalesced over col lanes
                unsigned short h1 = f2bf(x);
                a[t][0][s][j] = (short)h1;
                a[t][1][s][j] = (short)f2bf(x - bf2f(h1));
            }
    }

    float best[2][4], best2[2][4];
    int   bidx[2][4];
#pragma unroll
    for (int t = 0; t < 2; ++t)
#pragma unroll
        for (int r = 0; r < 4; ++r) {
            best[t][r] = -3.4e38f; best2[t][r] = -3.4e38f; bidx[t][r] = 0;
        }

    const short8* Bg = (const short8*)wsB;
    auto loadB = [&](short8* B, int i) {   // 4 level-1/2 frags of chunk
        const short8* p = Bg + (size_t)(cbase + i) * (FRAGS * 64) + lane;
        B[0] = p[0 * 64];                  // g1 kh0  (1 KB coalesced each)
        B[1] = p[1 * 64];                  // g1 kh1
        B[2] = p[2 * 64];                  // g2 kh0
        B[3] = p[3 * 64];                  // g2 kh1
    };
    auto ldn = [&](int i) { return wsN[(cbase + i) * 16 + col]; };

    auto compute = [&](const short8* B, float nrm, int i) {
        const int code = (cbase + i) * 16 + col;
#pragma unroll
        for (int t = 0; t < 2; ++t) {
            f32x4 acc = {nrm, nrm, nrm, nrm};
            acc = __builtin_amdgcn_mfma_f32_16x16x32_bf16(a[t][1][0], B[0], acc, 0, 0, 0);
            acc = __builtin_amdgcn_mfma_f32_16x16x32_bf16(a[t][1][1], B[1], acc, 0, 0, 0);
            acc = __builtin_amdgcn_mfma_f32_16x16x32_bf16(a[t][0][0], B[2], acc, 0, 0, 0);
            acc = __builtin_amdgcn_mfma_f32_16x16x32_bf16(a[t][0][1], B[3], acc, 0, 0, 0);
            acc = __builtin_amdgcn_mfma_f32_16x16x32_bf16(a[t][0][0], B[0], acc, 0, 0, 0);
            acc = __builtin_amdgcn_mfma_f32_16x16x32_bf16(a[t][0][1], B[1], acc, 0, 0, 0);
#pragma unroll
            for (int r = 0; r < 4; ++r) {
                float sc = acc[r];
                // med3(new, best, best2) == updated second-best
                best2[t][r] = __builtin_amdgcn_fmed3f(sc, best[t][r], best2[t][r]);
                bool gt = sc > best[t][r];
                bidx[t][r] = gt ? code : bidx[t][r];
                best[t][r] = fmaxf(best[t][r], sc);
            }
        }
    };

    // software pipeline, register double buffer, no LDS, no barriers
    short8 B0[4], B1[4];
    float  n0, n1;
    loadB(B0, 0); n0 = ldn(0);
    for (int i = 0; i < 128; i += 2) {
        loadB(B1, i + 1); n1 = ldn(i + 1);
        compute(B0, n0, i);
        if (i + 2 < 128) { loadB(B0, i + 2); n0 = ldn(i + 2); }
        compute(B1, n1, i + 1);
    }

    // top-2 merge across the 16 cols of each quad group
#pragma unroll
    for (int off = 1; off < 16; off <<= 1)
#pragma unroll
        for (int t = 0; t < 2; ++t)
#pragma unroll
            for (int r = 0; r < 4; ++r) {
                float os1 = __shfl_xor(best[t][r],  off, 64);
                int   oi1 = __shfl_xor(bidx[t][r],  off, 64);
                float os2 = __shfl_xor(best2[t][r], off, 64);
                bool take = (os1 > best[t][r]) ||
                            (os1 == best[t][r] && oi1 < bidx[t][r]);
                float ns2 = take ? fmaxf(best[t][r], os2)
                                 : fmaxf(best2[t][r], os1);
                if (take) { best[t][r] = os1; bidx[t][r] = oi1; }
                best2[t][r] = ns2;
            }
    if (col == 0)
#pragma unroll
        for (int t = 0; t < 2; ++t)
#pragma unroll
            for (int r = 0; r < 4; ++r) {
                int tokb = tg * 32 + t * 16 + quad * 4 + r;
                sS1[half][tokb] = best[t][r];
                sS2[half][tokb] = best2[t][r];
                sI1[half][tokb] = bidx[t][r];
            }
    __syncthreads();

    // combine halves per token (R11-verbatim 2-way merge); uncertain -> list
    if (threadIdx.x < 64) {
        const int tk = threadIdx.x;
        float b0 = sS1[0][tk], b1 = sS1[1][tk];
        int   i0 = sI1[0][tk], i1 = sI1[1][tk];
        float q0 = sS2[0][tk], q1 = sS2[1][tk];
        bool take1 = b1 > b0;              // tie -> half0 (lower idx)
        float bw = take1 ? b1 : b0;
        float bl = take1 ? b0 : b1;
        float qw = take1 ? q1 : q0;
        sOut[tk] = take1 ? i1 : i0;
        float second = fmaxf(qw, bl);
        if (bw - second < DELTA) {
            int s = atomicAdd(&sUCnt, 1);  // LDS atomic
            sUList[s] = tk;
        }
    }
    __syncthreads();

    // gather-write for ALL tokens (uncertain corrected below; barrier's
    // vmem drain orders the overwrite after this write)
    {
        const int tk   = threadIdx.x & 63;
        const int coff = (threadIdx.x >> 6) * 16;
        const int gt   = blockIdx.x * 64 + tk;
        const int ob   = gt >> 12, ohw = gt & 4095;
        float* op = out + ob * 262144 + ohw;
        const float4* ep = (const float4*)(emb + sOut[tk] * 64 + coff);
#pragma unroll
        for (int i = 0; i < 4; ++i) {
            float4 v = ep[i];
            op[(coff + 4 * i + 0) * 4096] = v.x;
            op[(coff + 4 * i + 1) * 4096] = v.y;
            op[(coff + 4 * i + 2) * 4096] = v.z;
            op[(coff + 4 * i + 3) * 4096] = v.w;
        }
    }
    __syncthreads();

    // ---- repair tail: bf16x3 6-term exact-class rescore (R5 numerics) ----
    const int cnt = sUCnt;
    for (int T0 = 0; T0 < cnt; T0 += 16) {
        int slot = T0 + col;
        if (slot >= cnt) slot = cnt - 1;   // duplicates benign
        const int tokb = sUList[slot];
        const int gt2  = blockIdx.x * 64 + tokb;
        const int b2   = gt2 >> 12, hw2 = gt2 & 4095;
        const float* zp2 = z + b2 * 262144 + hw2;

        short8 af[3][2];
#pragma unroll
        for (int s = 0; s < 2; ++s)
#pragma unroll
            for (int j = 0; j < 8; ++j) {
                int k = s * 32 + quad * 8 + j;
                float x = zp2[k * 4096];
                unsigned short h1 = f2bf(x);
                float r1 = x - bf2f(h1);
                unsigned short h2 = f2bf(r1);
                float r2 = r1 - bf2f(h2);
                af[0][s][j] = (short)h1;
                af[1][s][j] = (short)h2;
                af[2][s][j] = (short)f2bf(r2);
            }

        float rb[4] = {-3.4e38f, -3.4e38f, -3.4e38f, -3.4e38f};
        int   ri[4] = {0, 0, 0, 0};

        auto ldf = [&](short8* F, int ck) {      // all 6 frags of chunk ck
            const short8* p = Bg + (size_t)ck * (FRAGS * 64) + lane;
#pragma unroll
            for (int q = 0; q < 6; ++q) F[q] = p[q * 64];
        };
        auto rstep = [&](const short8* F, int ck) {
            const float nnrm = wsN[ck * 16 + col];
            const int   code = ck * 16 + col;
            f32x4 accA = {0.f, 0.f, 0.f, 0.f};
            f32x4 accB = {0.f, 0.f, 0.f, 0.f};
            accA = __builtin_amdgcn_mfma_f32_16x16x32_bf16(af[1][0], F[2], accA, 0, 0, 0);
            accB = __builtin_amdgcn_mfma_f32_16x16x32_bf16(af[0][0], F[2], accB, 0, 0, 0);
            accA = __builtin_amdgcn_mfma_f32_16x16x32_bf16(af[1][1], F[3], accA, 0, 0, 0);
            accB = __builtin_amdgcn_mfma_f32_16x16x32_bf16(af[0][1], F[3], accB, 0, 0, 0);
            accA = __builtin_amdgcn_mfma_f32_16x16x32_bf16(af[0][0], F[4], accA, 0, 0, 0);
            accB = __builtin_amdgcn_mfma_f32_16x16x32_bf16(af[1][0], F[0], accB, 0, 0, 0);
            accA = __builtin_amdgcn_mfma_f32_16x16x32_bf16(af[0][1], F[5], accA, 0, 0, 0);
            accB = __builtin_amdgcn_mfma_f32_16x16x32_bf16(af[1][1], F[1], accB, 0, 0, 0);
            accA = __builtin_amdgcn_mfma_f32_16x16x32_bf16(af[2][0], F[0], accA, 0, 0, 0);
            accB = __builtin_amdgcn_mfma_f32_16x16x32_bf16(af[0][0], F[0], accB, 0, 0, 0);
            accA = __builtin_amdgcn_mfma_f32_16x16x32_bf16(af[2][1], F[1], accA, 0, 0, 0);
            accB = __builtin_amdgcn_mfma_f32_16x16x32_bf16(af[0][1], F[1], accB, 0, 0, 0);
#pragma unroll
            for (int r = 0; r < 4; ++r) {
                float score = (accA[r] + accB[r]) + nnrm;
                if (score > rb[r]) { rb[r] = score; ri[r] = code; }
            }
        };

        // wave covers 64 chunks, register-double-buffered (R11-verbatim)
        const int ck0 = wave * 64;
        short8 F0[6], F1[6];
        ldf(F0, ck0);
        for (int i = 0; i < 64; i += 2) {
            ldf(F1, ck0 + i + 1);
            rstep(F0, ck0 + i);
            if (i + 2 < 64) ldf(F0, ck0 + i + 2);
            rstep(F1, ck0 + i + 1);
        }

#pragma unroll
        for (int off = 1; off < 16; off <<= 1)
#pragma unroll
            for (int r = 0; r < 4; ++r) {
                float os = __shfl_xor(rb[r], off, 64);
                int   oi = __shfl_xor(ri[r], off, 64);
                if (os > rb[r] || (os == rb[r] && oi < ri[r])) {
                    rb[r] = os; ri[r] = oi;
                }
            }
        if (col == 0)
#pragma unroll
            for (int r = 0; r < 4; ++r) {
                sRS[wave][quad * 4 + r] = rb[r];
                sRI[wave][quad * 4 + r] = ri[r];
            }
        __syncthreads();

        if (threadIdx.x < 16) {            // waves cover ascending ranges
            float bs = sRS[0][threadIdx.x]; int bi = sRI[0][threadIdx.x];
#pragma unroll
            for (int w = 1; w < 4; ++w) {
                float s2 = sRS[w][threadIdx.x]; int i2 = sRI[w][threadIdx.x];
                if (s2 > bs || (s2 == bs && i2 < bi)) { bs = s2; bi = i2; }
            }
            sRI[0][threadIdx.x] = bi;
        }
        __syncthreads();

        {   // overwrite the repaired tokens' rows (dup rows write same data)
            const int row = threadIdx.x & 15;
            int rslot = T0 + row;
            if (rslot >= cnt) rslot = cnt - 1;
            const int cb  = (threadIdx.x >> 4) * 4;
            const int tk2 = sUList[rslot];
            const int g3  = blockIdx.x * 64 + tk2;
            const int bb  = g3 >> 12, hh = g3 & 4095;
            const float* e = emb + sRI[0][row] * 64;
            float* op = out + bb * 262144 + hh;
#pragma unroll
            for (int i = 0; i < 4; ++i)
                op[(cb + i) * 4096] = e[cb + i];
        }
        __syncthreads();                   // sRS/sRI reuse next tile
    }
}

// ---- fallback (proven Round-1 kernel; used only if ws is too small) ------
__global__ __launch_bounds__(256) void vq_fp32_kernel(
    const float* __restrict__ z, const float* __restrict__ emb,
    float* __restrict__ out)
{
    __shared__ float se[64 * 64];
    __shared__ float snorm[64];

    const int t  = blockIdx.x * 256 + threadIdx.x;
    const int b  = t >> 12;
    const int hw = t & 4095;
    const float* zt = z + (size_t)b * 262144 + hw;
    float zf[64];
#pragma unroll
    for (int c = 0; c < 64; ++c) zf[c] = zt[(size_t)c * 4096];

    float best = -3.4e38f;
    int   bestIdx = 0;
    for (int k0 = 0; k0 < 4096; k0 += 64) {
        __syncthreads();
        const float4* src = (const float4*)(emb + (size_t)k0 * 64);
        float4*       dst = (float4*)se;
#pragma unroll
        for (int i = 0; i < 4; ++i)
            dst[i * 256 + threadIdx.x] = src[i * 256 + threadIdx.x];
        __syncthreads();
        if (threadIdx.x < 64) {
            float s = 0.f;
#pragma unroll
            for (int c = 0; c < 64; ++c) {
                float v = se[threadIdx.x * 64 + c];
                s = fmaf(v, v, s);
            }
            snorm[threadIdx.x] = 0.5f * s;
        }
        __syncthreads();
#pragma unroll 4
        for (int kk = 0; kk < 64; ++kk) {
            float dot = 0.f;
#pragma unroll
            for (int c = 0; c < 64; ++c)
                dot = fmaf(zf[c], se[kk * 64 + c], dot);
            float score = dot - snorm[kk];
            if (score > best) { best = score; bestIdx = k0 + kk; }
        }
    }
    const float* e  = emb + (size_t)bestIdx * 64;
    float*       ot = out + (size_t)b * 262144 + hw;
#pragma unroll
    for (int c = 0; c < 64; ++c) ot[(size_t)c * 4096] = e[c];
}

extern "C" void kernel_launch(void* const* d_in, const int* in_sizes, int n_in,
                              void* d_out, int out_size, void* d_ws, size_t ws_size,
                              hipStream_t stream) {
    const float* z   = (const float*)d_in[0];
    const float* emb = (const float*)d_in[1];
    float*       out = (float*)d_out;

    if (ws_size < WS_NEEDED) {          // constant per session: graph-safe
        vq_fp32_kernel<<<256, 256, 0, stream>>>(z, emb, out);
        return;
    }

    unsigned short* wsB = (unsigned short*)d_ws;
    float*          wsN = (float*)((char*)d_ws + OFF_N);

    vq_pack_kernel<<<256, 384, 0, stream>>>(emb, wsB, wsN);
    vq_main_kernel<<<1024, 256, 0, stream>>>(z, emb, wsB, wsN, out);
}